// Round 6
// baseline (49738.055 us; speedup 1.0000x reference)
//
#include <hip/hip_runtime.h>
#include <math.h>

#define KW 24
#define BSZn 64
#define PLY 32
#define BROWS 1536            // BSZ*KW rows per task
#define RTOT 4608             // 3*BROWS
#define G4 2048

__device__ __forceinline__ float sigmoidf_(float x) { return 1.0f / (1.0f + expf(-x)); }

// W3[2560][1024]: n<2048 gate-interleaved (i,f,g,o per unit) [W_ih|W_hh];
// n>=2048: [0 | Wq[n-2048]]. bias3[2560] likewise.
__global__ void w3cat_kernel(const float* __restrict__ W_ih, const float* __restrict__ W_hh,
                             const float* __restrict__ Wq, const float* __restrict__ b_ih,
                             const float* __restrict__ b_hh, const float* __restrict__ bq,
                             float* __restrict__ W3, float* __restrict__ bias3)
{
    int n = blockIdx.x;          // 0..2559
    int tid = threadIdx.x;
    float* w = W3 + (size_t)n * 1024;
    if (n < G4) {
        int src = (n & 3) * 512 + (n >> 2);
        for (int k = tid; k < 512; k += blockDim.x) {
            w[k]       = W_ih[(size_t)src * 512 + k];
            w[512 + k] = W_hh[(size_t)src * 512 + k];
        }
        if (tid == 0) bias3[n] = b_ih[src] + b_hh[src];
    } else {
        int j = n - G4;
        for (int k = tid; k < 512; k += blockDim.x) {
            w[k]       = 0.0f;
            w[512 + k] = Wq[(size_t)j * 512 + k];
        }
        if (tid == 0) bias3[n] = bq[j];
    }
}

// h0 = enc.sum(axis=1) -> hbuf0 and cst
__global__ void h0init_kernel(const float* __restrict__ home, const float* __restrict__ vis,
                              const float* __restrict__ team,
                              float* __restrict__ hbuf0, float* __restrict__ cst)
{
    int row = blockIdx.x;                 // 0..4607
    int tid = threadIdx.x;                // 256
    int tau = row / BROWS, r = row % BROWS;
    int bb = r / KW, kw = r % KW;
    const float* enc = (tau == 0) ? home : (tau == 1) ? vis : team;
    const float* base = enc + ((size_t)(kw * BSZn + bb) * PLY) * 512;
    for (int e = tid; e < 512; e += blockDim.x) {
        float s = 0.0f;
        for (int p = 0; p < PLY; ++p) s += base[(size_t)p * 512 + e];
        hbuf0[(size_t)row * 512 + e] = s;
        cst[(size_t)row * 512 + e] = s;
    }
}

// ---- mega kernel: [gate | q | attn | ctx] block ranges ----
// GEMM: BM=BN=128, BK=16, 256 thr, 8x8/thread, LDS ping-pong (1 barrier/tile).
// Bs layout [k][h:2][72]: col n -> (h=(n>>2)&1, tn=n>>3, w=n&3) at [h][tn*4+w]:
// reads are 256B-contiguous per instr (2-way, free), stores conflict-free.
__global__ __launch_bounds__(256, 4) void step_k(
    const float* __restrict__ home, const float* __restrict__ vis, const float* __restrict__ team,
    const int* __restrict__ hidx, const int* __restrict__ vidx, const int* __restrict__ tidx,
    const float* __restrict__ init_embed,
    const float* __restrict__ W3, const float* __restrict__ bias3,
    const float* __restrict__ Wc,
    const float* __restrict__ hin, float* __restrict__ hout,
    float* __restrict__ cst, float* __restrict__ Q5,
    float* __restrict__ ctx, const float* __restrict__ vvec,
    float* __restrict__ out,
    int t, int ng, int nq, int na, int ctx_off, int tbase)
{
    __shared__ float As[2][16][132];
    __shared__ float Bs[2][16][2][72];
    __shared__ float scs[4][32];
    int bid = blockIdx.x, tid = threadIdx.x;

    if (bid < ng + nq) {
        // ---------------- gate / q GEMM ----------------
        bool isg = bid < ng;
        int bm, cb, Kt, koff, nbase;
        if (isg) { bm = bid >> 4; cb = bid & 15; Kt = 64; koff = 0;   nbase = cb * 128; }
        else     { int qb = bid - ng; bm = qb >> 2; cb = qb & 3; Kt = 32; koff = 512; nbase = G4 + cb * 128; }
        int tm = tid >> 4, tn = tid & 15;
        int lrow = tid >> 2, lc4 = tid & 3;

        int Rl0 = bm * 128 + lrow, Rl1 = Rl0 + 64;
        const float* hs0 = hin + (size_t)Rl0 * 512 - 512;   // indexed by k in [512,1024)
        const float* hs1 = hin + (size_t)Rl1 * 512 - 512;
        const float* xs0 = init_embed;
        const float* xs1 = init_embed;
        if (isg && t > 0) {
            int tau = (bm * 128) / BROWS;
            const float* enc = (tau == 0) ? home : (tau == 1) ? vis : team;
            const int* idx = (tau == 0) ? hidx : (tau == 1) ? vidx : tidx;
            int r0 = Rl0 - tau * BROWS, r1 = Rl1 - tau * BROWS;
            int j0 = idx[r0 * PLY + (t - 1)];
            int j1 = idx[r1 * PLY + (t - 1)];
            xs0 = enc + (((size_t)((r0 % KW) * BSZn + r0 / KW)) * PLY + j0) * 512;
            xs1 = enc + (((size_t)((r1 % KW) * BSZn + r1 / KW)) * PLY + j1) * 512;
        }
        const float* bp0 = W3 + (size_t)(nbase + lrow) * 1024;
        const float* bp1 = W3 + (size_t)(nbase + lrow + 64) * 1024;
        int h0 = (lrow >> 2) & 1, tn0 = lrow >> 3, w0 = lrow & 3;           // n0 = lrow
        int n1 = lrow + 64;
        int h1 = (n1 >> 2) & 1,  tn1 = n1 >> 3,  w1 = n1 & 3;

        float acc[8][8];
        #pragma unroll
        for (int i = 0; i < 8; ++i)
            #pragma unroll
            for (int j = 0; j < 8; ++j) acc[i][j] = 0.0f;

        int k0 = koff + lc4 * 4;
        bool x0 = (isg && k0 < 512);
        float4 ra0 = *(const float4*)((x0 ? xs0 : hs0) + k0);
        float4 ra1 = *(const float4*)((x0 ? xs1 : hs1) + k0);
        float4 rb0 = *(const float4*)(bp0 + k0);
        float4 rb1 = *(const float4*)(bp1 + k0);

        for (int it = 0; it < Kt; ++it) {
            int buf = it & 1;
            #pragma unroll
            for (int j = 0; j < 4; ++j) {
                As[buf][lc4 * 4 + j][lrow]          = ((const float*)&ra0)[j];
                As[buf][lc4 * 4 + j][lrow + 64]     = ((const float*)&ra1)[j];
                Bs[buf][lc4 * 4 + j][h0][tn0 * 4 + w0] = ((const float*)&rb0)[j];
                Bs[buf][lc4 * 4 + j][h1][tn1 * 4 + w1] = ((const float*)&rb1)[j];
            }
            __syncthreads();
            if (it + 1 < Kt) {
                int k2 = koff + (it + 1) * 16 + lc4 * 4;
                bool xk = (isg && k2 < 512);
                ra0 = *(const float4*)((xk ? xs0 : hs0) + k2);
                ra1 = *(const float4*)((xk ? xs1 : hs1) + k2);
                rb0 = *(const float4*)(bp0 + k2);
                rb1 = *(const float4*)(bp1 + k2);
            }
            #pragma unroll
            for (int kk = 0; kk < 16; ++kk) {
                float af[8], bf[8];
                *(float4*)&af[0] = *(const float4*)&As[buf][kk][tm * 8];
                *(float4*)&af[4] = *(const float4*)&As[buf][kk][tm * 8 + 4];
                *(float4*)&bf[0] = *(const float4*)&Bs[buf][kk][0][tn * 4];
                *(float4*)&bf[4] = *(const float4*)&Bs[buf][kk][1][tn * 4];
                #pragma unroll
                for (int i = 0; i < 8; ++i)
                    #pragma unroll
                    for (int j = 0; j < 8; ++j)
                        acc[i][j] = fmaf(af[i], bf[j], acc[i][j]);
            }
        }

        int row0 = bm * 128 + tm * 8;
        if (isg) {
            int gcol = cb * 128 + tn * 8;
            int u0 = gcol >> 2;
            float bv[8];
            *(float4*)&bv[0] = *(const float4*)&bias3[gcol];
            *(float4*)&bv[4] = *(const float4*)&bias3[gcol + 4];
            #pragma unroll
            for (int i = 0; i < 8; ++i) {
                int row = row0 + i;
                float2 c = *(float2*)(cst + (size_t)row * 512 + u0);
                float gi = acc[i][0] + bv[0], gf = acc[i][1] + bv[1];
                float gg = acc[i][2] + bv[2], go = acc[i][3] + bv[3];
                c.x = sigmoidf_(gf) * c.x + sigmoidf_(gi) * tanhf(gg);
                float hv0 = sigmoidf_(go) * tanhf(c.x);
                gi = acc[i][4] + bv[4]; gf = acc[i][5] + bv[5];
                gg = acc[i][6] + bv[6]; go = acc[i][7] + bv[7];
                c.y = sigmoidf_(gf) * c.y + sigmoidf_(gi) * tanhf(gg);
                float hv1 = sigmoidf_(go) * tanhf(c.y);
                *(float2*)(cst + (size_t)row * 512 + u0) = c;
                float2 hh; hh.x = hv0; hh.y = hv1;
                *(float2*)(hout + (size_t)row * 512 + u0) = hh;
            }
        } else {
            int qcol = cb * 128 + tn * 8;
            int slot = (t - 1) % 5;
            float bv[8];
            *(float4*)&bv[0] = *(const float4*)&bias3[G4 + qcol];
            *(float4*)&bv[4] = *(const float4*)&bias3[G4 + qcol + 4];
            #pragma unroll
            for (int i = 0; i < 8; ++i) {
                float* qp = Q5 + ((size_t)(row0 + i) * 5 + slot) * 512 + qcol;
                float4 o0, o1;
                o0.x = acc[i][0] + bv[0]; o0.y = acc[i][1] + bv[1];
                o0.z = acc[i][2] + bv[2]; o0.w = acc[i][3] + bv[3];
                o1.x = acc[i][4] + bv[4]; o1.y = acc[i][5] + bv[5];
                o1.z = acc[i][6] + bv[6]; o1.w = acc[i][7] + bv[7];
                *(float4*)qp = o0;
                *(float4*)(qp + 4) = o1;
            }
        }
    } else if (bid < ng + nq + na) {
        // ---------------- attention: 4 waves, wave w -> step tbase+w ----------------
        int row = bid - ng - nq;              // 0..4607
        int w = tid >> 6, lane = tid & 63;
        int tc = tbase + w;
        const float* q = Q5 + ((size_t)row * 5 + (tc % 5)) * 512 + lane * 8;
        const float* ctxr = ctx + ((size_t)row * PLY) * 512 + lane * 8;
        float qv[8], vv[8];
        *(float4*)&qv[0] = *(const float4*)(q);
        *(float4*)&qv[4] = *(const float4*)(q + 4);
        *(float4*)&vv[0] = *(const float4*)(vvec + lane * 8);
        *(float4*)&vv[4] = *(const float4*)(vvec + lane * 8 + 4);

        for (int p = 0; p < PLY; ++p) {
            const float* cp = ctxr + (size_t)p * 512;
            float cv[8];
            *(float4*)&cv[0] = *(const float4*)(cp);
            *(float4*)&cv[4] = *(const float4*)(cp + 4);
            float acc = 0.0f;
            #pragma unroll
            for (int j = 0; j < 8; ++j) acc += tanhf(qv[j] + cv[j]) * vv[j];
            #pragma unroll
            for (int off = 1; off < 64; off <<= 1) acc += __shfl_xor(acc, off);
            if (lane == 0) scs[w][p] = acc;
        }
        __syncthreads();

        if (tid < 128) {
            int w2 = tid >> 5, l = tid & 31;
            float x = scs[w2][l];
            float bvv = x; int bi = l;
            #pragma unroll
            for (int off = 1; off < 32; off <<= 1) {
                float ov = __shfl_xor(bvv, off, 32);
                int oi = __shfl_xor(bi, off, 32);
                if (ov > bvv || (ov == bvv && oi < bi)) { bvv = ov; bi = oi; }
            }
            float s = expf(x - bvv);
            #pragma unroll
            for (int off = 1; off < 32; off <<= 1) s += __shfl_xor(s, off, 32);
            float lse = logf(s);
            int tt = tbase + w2;
            int tau = row / BROWS, r = row % BROWS;
            out[(size_t)tau * (BROWS * 1024) + (size_t)r * 1024 + tt * 32 + l] = x - bvv - lse;
            if (l == 0)
                out[(size_t)3 * (BROWS * 1024) + (size_t)tau * (BROWS * 32) + r * 32 + tt] = (float)bi;
        }
    } else {
        // ---------------- ctx GEMM: ctx = enc @ Wc^T ----------------
        int cp = bid - (ng + nq + na) + ctx_off;
        int pan = cp >> 2, cb = cp & 3;
        int tm = tid >> 4, tn = tid & 15;
        int lrow = tid >> 2, lc4 = tid & 3;

        int R0 = pan * 128 + lrow, R1 = R0 + 64;
        int tau = (pan * 128) / (BROWS * PLY);
        const float* enc = (tau == 0) ? home : (tau == 1) ? vis : team;
        int rr0 = R0 % (BROWS * PLY), r0 = rr0 >> 5, p0 = rr0 & 31;
        int rr1 = R1 % (BROWS * PLY), r1 = rr1 >> 5, p1 = rr1 & 31;
        const float* es0 = enc + (((size_t)((r0 % KW) * BSZn + r0 / KW)) * PLY + p0) * 512;
        const float* es1 = enc + (((size_t)((r1 % KW) * BSZn + r1 / KW)) * PLY + p1) * 512;
        const float* bp0 = Wc + (size_t)(cb * 128 + lrow) * 512;
        const float* bp1 = bp0 + (size_t)64 * 512;
        int h0 = (lrow >> 2) & 1, tn0 = lrow >> 3, w0 = lrow & 3;
        int n1 = lrow + 64;
        int h1 = (n1 >> 2) & 1,  tn1 = n1 >> 3,  w1 = n1 & 3;

        float acc[8][8];
        #pragma unroll
        for (int i = 0; i < 8; ++i)
            #pragma unroll
            for (int j = 0; j < 8; ++j) acc[i][j] = 0.0f;

        float4 ra0 = *(const float4*)(es0 + lc4 * 4);
        float4 ra1 = *(const float4*)(es1 + lc4 * 4);
        float4 rb0 = *(const float4*)(bp0 + lc4 * 4);
        float4 rb1 = *(const float4*)(bp1 + lc4 * 4);

        for (int it = 0; it < 32; ++it) {
            int buf = it & 1;
            #pragma unroll
            for (int j = 0; j < 4; ++j) {
                As[buf][lc4 * 4 + j][lrow]          = ((const float*)&ra0)[j];
                As[buf][lc4 * 4 + j][lrow + 64]     = ((const float*)&ra1)[j];
                Bs[buf][lc4 * 4 + j][h0][tn0 * 4 + w0] = ((const float*)&rb0)[j];
                Bs[buf][lc4 * 4 + j][h1][tn1 * 4 + w1] = ((const float*)&rb1)[j];
            }
            __syncthreads();
            if (it + 1 < 32) {
                int k2 = (it + 1) * 16 + lc4 * 4;
                ra0 = *(const float4*)(es0 + k2);
                ra1 = *(const float4*)(es1 + k2);
                rb0 = *(const float4*)(bp0 + k2);
                rb1 = *(const float4*)(bp1 + k2);
            }
            #pragma unroll
            for (int kk = 0; kk < 16; ++kk) {
                float af[8], bf[8];
                *(float4*)&af[0] = *(const float4*)&As[buf][kk][tm * 8];
                *(float4*)&af[4] = *(const float4*)&As[buf][kk][tm * 8 + 4];
                *(float4*)&bf[0] = *(const float4*)&Bs[buf][kk][0][tn * 4];
                *(float4*)&bf[4] = *(const float4*)&Bs[buf][kk][1][tn * 4];
                #pragma unroll
                for (int i = 0; i < 8; ++i)
                    #pragma unroll
                    for (int j = 0; j < 8; ++j)
                        acc[i][j] = fmaf(af[i], bf[j], acc[i][j]);
            }
        }
        int row0 = pan * 128 + tm * 8;
        int col0 = cb * 128 + tn * 8;
        #pragma unroll
        for (int i = 0; i < 8; ++i) {
            float* cr = ctx + (size_t)(row0 + i) * 512 + col0;
            float4 o0, o1;
            o0.x = acc[i][0]; o0.y = acc[i][1]; o0.z = acc[i][2]; o0.w = acc[i][3];
            o1.x = acc[i][4]; o1.y = acc[i][5]; o1.z = acc[i][6]; o1.w = acc[i][7];
            *(float4*)cr = o0;
            *(float4*)(cr + 4) = o1;
        }
    }
}

extern "C" void kernel_launch(void* const* d_in, const int* in_sizes, int n_in,
                              void* d_out, int out_size, void* d_ws, size_t ws_size,
                              hipStream_t stream)
{
    const float* home = (const float*)d_in[0];
    const int*   hidx = (const int*)d_in[1];
    const float* vis  = (const float*)d_in[2];
    const int*   vidx = (const int*)d_in[3];
    const float* team = (const float*)d_in[4];
    const int*   tidx = (const int*)d_in[5];
    const float* init_embed = (const float*)d_in[6];
    const float* W_ih = (const float*)d_in[7];
    const float* W_hh = (const float*)d_in[8];
    const float* b_ih = (const float*)d_in[9];
    const float* b_hh = (const float*)d_in[10];
    const float* Wq   = (const float*)d_in[11];
    const float* bq   = (const float*)d_in[12];
    const float* Wc   = (const float*)d_in[13];
    const float* vvec = (const float*)d_in[14];
    float* out = (float*)d_out;
    (void)in_sizes; (void)n_in; (void)out_size; (void)ws_size;

    float* ws = (float*)d_ws;
    float* W3    = ws; ws += (size_t)2560 * 1024;   // 10.5 MB
    float* bias3 = ws; ws += 2560;
    float* hbuf0 = ws; ws += (size_t)RTOT * 512;
    float* hbuf1 = ws; ws += (size_t)RTOT * 512;
    float* cst   = ws; ws += (size_t)RTOT * 512;
    float* Q5    = ws; ws += (size_t)RTOT * 5 * 512; // 47.2 MB
    float* ctx   = ws;                               // 302 MB f32; total ~387.9 MB

    const int NG = 576;    // 36 row-panels x 16 gate col-blocks (128 cols)
    const int NQ = 144;    // 36 x 4 q col-blocks
    const int NA = RTOT;   // attn blocks
    const int NCTX_PER = 1152;  // ctx blocks per launch, t=0..3 (total 4608)

    w3cat_kernel<<<2560, 256, 0, stream>>>(W_ih, W_hh, Wq, b_ih, b_hh, bq, W3, bias3);
    h0init_kernel<<<RTOT, 256, 0, stream>>>(home, vis, team, hbuf0, cst);

    for (int t = 0; t <= 32; ++t) {
        int ng = (t < 32) ? NG : 0;
        int nq = (t >= 1) ? NQ : 0;
        int tbase = (t >= 5 && t <= 29 && ((t - 5) & 3) == 0) ? (t - 5) : -1;
        int na = (tbase >= 0) ? NA : 0;
        int nc = (t < 4) ? NCTX_PER : 0;
        const float* hin = (t & 1) ? hbuf1 : hbuf0;
        float* hout = (t & 1) ? hbuf0 : hbuf1;
        step_k<<<ng + nq + na + nc, 256, 0, stream>>>(
            home, vis, team, hidx, vidx, tidx, init_embed,
            W3, bias3, Wc, hin, hout, cst, Q5, ctx, vvec, out,
            t, ng, nq, na, t * NCTX_PER, tbase);
    }
    // final attention batch: steps 28..31 (q31 written by the t=32 launch)
    step_k<<<NA, 256, 0, stream>>>(
        home, vis, team, hidx, vidx, tidx, init_embed,
        W3, bias3, Wc, hbuf0, hbuf1, cst, Q5, ctx, vvec, out,
        33, 0, 0, NA, 0, 28);
}

// Round 7
// 19693.274 us; speedup vs baseline: 2.5256x; 2.5256x over previous
//
#include <hip/hip_runtime.h>
#include <math.h>

#define KW 24
#define BSZn 64
#define PLY 32
#define BROWS 1536            // BSZ*KW rows per task
#define RTOT 4608             // 3*BROWS
#define G4 2048

__device__ __forceinline__ float sigmoidf_(float x) { return 1.0f / (1.0f + expf(-x)); }

// W3[2560][1024]: n<2048 gate-interleaved (i,f,g,o per unit) [W_ih|W_hh];
// n>=2048: [0 | Wq[n-2048]]. bias3[2560] likewise.
__global__ void w3cat_kernel(const float* __restrict__ W_ih, const float* __restrict__ W_hh,
                             const float* __restrict__ Wq, const float* __restrict__ b_ih,
                             const float* __restrict__ b_hh, const float* __restrict__ bq,
                             float* __restrict__ W3, float* __restrict__ bias3)
{
    int n = blockIdx.x;          // 0..2559
    int tid = threadIdx.x;
    float* w = W3 + (size_t)n * 1024;
    if (n < G4) {
        int src = (n & 3) * 512 + (n >> 2);
        for (int k = tid; k < 512; k += blockDim.x) {
            w[k]       = W_ih[(size_t)src * 512 + k];
            w[512 + k] = W_hh[(size_t)src * 512 + k];
        }
        if (tid == 0) bias3[n] = b_ih[src] + b_hh[src];
    } else {
        int j = n - G4;
        for (int k = tid; k < 512; k += blockDim.x) {
            w[k]       = 0.0f;
            w[512 + k] = Wq[(size_t)j * 512 + k];
        }
        if (tid == 0) bias3[n] = bq[j];
    }
}

// h0 = enc.sum(axis=1) -> hbuf0 and cst
__global__ void h0init_kernel(const float* __restrict__ home, const float* __restrict__ vis,
                              const float* __restrict__ team,
                              float* __restrict__ hbuf0, float* __restrict__ cst)
{
    int row = blockIdx.x;                 // 0..4607
    int tid = threadIdx.x;                // 256
    int tau = row / BROWS, r = row % BROWS;
    int bb = r / KW, kw = r % KW;
    const float* enc = (tau == 0) ? home : (tau == 1) ? vis : team;
    const float* base = enc + ((size_t)(kw * BSZn + bb) * PLY) * 512;
    for (int e = tid; e < 512; e += blockDim.x) {
        float s = 0.0f;
        for (int p = 0; p < PLY; ++p) s += base[(size_t)p * 512 + e];
        hbuf0[(size_t)row * 512 + e] = s;
        cst[(size_t)row * 512 + e] = s;
    }
}

// ---- mega kernel: [gate | q | attn | ctx] block ranges ----
// GEMM: BM=BN=128, BK=16, 256 thr, 8x8/thread, LDS ping-pong (1 barrier/tile).
// Bs layout [k][h:2][73]: col n -> (h=(n>>2)&1, tn=n>>3, w=n&3) at [h][tn*4+w].
// Reads: lanes 0..15 span 256B contiguous (2-way, free). Stores: rows r,r+4,r+8,r+12
// differ by 4*146 dwords = 8 mod 32 -> banks {0,8,16,24}, conflict-free (73-pad).
// NOTE R6 lesson: __launch_bounds__ 2nd arg caps VGPR (~256/arg) -> spills; use (256).
__global__ __launch_bounds__(256) void step_k(
    const float* __restrict__ home, const float* __restrict__ vis, const float* __restrict__ team,
    const int* __restrict__ hidx, const int* __restrict__ vidx, const int* __restrict__ tidx,
    const float* __restrict__ init_embed,
    const float* __restrict__ W3, const float* __restrict__ bias3,
    const float* __restrict__ Wc,
    const float* __restrict__ hin, float* __restrict__ hout,
    float* __restrict__ cst, float* __restrict__ Q5,
    float* __restrict__ ctx, const float* __restrict__ vvec,
    float* __restrict__ out,
    int t, int ng, int nq, int na, int ctx_off, int tbase)
{
    __shared__ float As[2][16][132];
    __shared__ float Bs[2][16][2][73];
    __shared__ float scs[4][32];
    int bid = blockIdx.x, tid = threadIdx.x;

    if (bid < ng + nq) {
        // ---------------- gate / q GEMM ----------------
        bool isg = bid < ng;
        int bm, cb, Kt, koff, nbase;
        if (isg) { bm = bid >> 4; cb = bid & 15; Kt = 64; koff = 0;   nbase = cb * 128; }
        else     { int qb = bid - ng; bm = qb >> 2; cb = qb & 3; Kt = 32; koff = 512; nbase = G4 + cb * 128; }
        int tm = tid >> 4, tn = tid & 15;
        int lrow = tid >> 2, lc4 = tid & 3;

        int Rl0 = bm * 128 + lrow, Rl1 = Rl0 + 64;
        const float* hs0 = hin + (size_t)Rl0 * 512 - 512;   // indexed by k in [512,1024)
        const float* hs1 = hin + (size_t)Rl1 * 512 - 512;
        const float* xs0 = init_embed;
        const float* xs1 = init_embed;
        if (isg && t > 0) {
            int tau = (bm * 128) / BROWS;
            const float* enc = (tau == 0) ? home : (tau == 1) ? vis : team;
            const int* idx = (tau == 0) ? hidx : (tau == 1) ? vidx : tidx;
            int r0 = Rl0 - tau * BROWS, r1 = Rl1 - tau * BROWS;
            int j0 = idx[r0 * PLY + (t - 1)];
            int j1 = idx[r1 * PLY + (t - 1)];
            xs0 = enc + (((size_t)((r0 % KW) * BSZn + r0 / KW)) * PLY + j0) * 512;
            xs1 = enc + (((size_t)((r1 % KW) * BSZn + r1 / KW)) * PLY + j1) * 512;
        }
        const float* bp0 = W3 + (size_t)(nbase + lrow) * 1024;
        const float* bp1 = W3 + (size_t)(nbase + lrow + 64) * 1024;
        int h0 = (lrow >> 2) & 1, tn0 = lrow >> 3, w0 = lrow & 3;           // n0 = lrow
        int n1 = lrow + 64;
        int h1 = (n1 >> 2) & 1,  tn1 = n1 >> 3,  w1 = n1 & 3;

        float acc[8][8];
        #pragma unroll
        for (int i = 0; i < 8; ++i)
            #pragma unroll
            for (int j = 0; j < 8; ++j) acc[i][j] = 0.0f;

        int k0 = koff + lc4 * 4;
        bool x0 = (isg && k0 < 512);
        float4 ra0 = *(const float4*)((x0 ? xs0 : hs0) + k0);
        float4 ra1 = *(const float4*)((x0 ? xs1 : hs1) + k0);
        float4 rb0 = *(const float4*)(bp0 + k0);
        float4 rb1 = *(const float4*)(bp1 + k0);

        for (int it = 0; it < Kt; ++it) {
            int buf = it & 1;
            #pragma unroll
            for (int j = 0; j < 4; ++j) {
                As[buf][lc4 * 4 + j][lrow]          = ((const float*)&ra0)[j];
                As[buf][lc4 * 4 + j][lrow + 64]     = ((const float*)&ra1)[j];
                Bs[buf][lc4 * 4 + j][h0][tn0 * 4 + w0] = ((const float*)&rb0)[j];
                Bs[buf][lc4 * 4 + j][h1][tn1 * 4 + w1] = ((const float*)&rb1)[j];
            }
            __syncthreads();
            if (it + 1 < Kt) {
                int k2 = koff + (it + 1) * 16 + lc4 * 4;
                bool xk = (isg && k2 < 512);
                ra0 = *(const float4*)((xk ? xs0 : hs0) + k2);
                ra1 = *(const float4*)((xk ? xs1 : hs1) + k2);
                rb0 = *(const float4*)(bp0 + k2);
                rb1 = *(const float4*)(bp1 + k2);
            }
            #pragma unroll
            for (int kk = 0; kk < 16; ++kk) {
                float af[8], bf[8];
                *(float4*)&af[0] = *(const float4*)&As[buf][kk][tm * 8];
                *(float4*)&af[4] = *(const float4*)&As[buf][kk][tm * 8 + 4];
                *(float4*)&bf[0] = *(const float4*)&Bs[buf][kk][0][tn * 4];
                *(float4*)&bf[4] = *(const float4*)&Bs[buf][kk][1][tn * 4];
                #pragma unroll
                for (int i = 0; i < 8; ++i)
                    #pragma unroll
                    for (int j = 0; j < 8; ++j)
                        acc[i][j] = fmaf(af[i], bf[j], acc[i][j]);
            }
        }

        int row0 = bm * 128 + tm * 8;
        if (isg) {
            int gcol = cb * 128 + tn * 8;
            int u0 = gcol >> 2;
            float bv[8];
            *(float4*)&bv[0] = *(const float4*)&bias3[gcol];
            *(float4*)&bv[4] = *(const float4*)&bias3[gcol + 4];
            #pragma unroll
            for (int i = 0; i < 8; ++i) {
                int row = row0 + i;
                float2 c = *(float2*)(cst + (size_t)row * 512 + u0);
                float gi = acc[i][0] + bv[0], gf = acc[i][1] + bv[1];
                float gg = acc[i][2] + bv[2], go = acc[i][3] + bv[3];
                c.x = sigmoidf_(gf) * c.x + sigmoidf_(gi) * tanhf(gg);
                float hv0 = sigmoidf_(go) * tanhf(c.x);
                gi = acc[i][4] + bv[4]; gf = acc[i][5] + bv[5];
                gg = acc[i][6] + bv[6]; go = acc[i][7] + bv[7];
                c.y = sigmoidf_(gf) * c.y + sigmoidf_(gi) * tanhf(gg);
                float hv1 = sigmoidf_(go) * tanhf(c.y);
                *(float2*)(cst + (size_t)row * 512 + u0) = c;
                float2 hh; hh.x = hv0; hh.y = hv1;
                *(float2*)(hout + (size_t)row * 512 + u0) = hh;
            }
        } else {
            int qcol = cb * 128 + tn * 8;
            int slot = (t - 1) % 5;
            float bv[8];
            *(float4*)&bv[0] = *(const float4*)&bias3[G4 + qcol];
            *(float4*)&bv[4] = *(const float4*)&bias3[G4 + qcol + 4];
            #pragma unroll
            for (int i = 0; i < 8; ++i) {
                float* qp = Q5 + ((size_t)(row0 + i) * 5 + slot) * 512 + qcol;
                float4 o0, o1;
                o0.x = acc[i][0] + bv[0]; o0.y = acc[i][1] + bv[1];
                o0.z = acc[i][2] + bv[2]; o0.w = acc[i][3] + bv[3];
                o1.x = acc[i][4] + bv[4]; o1.y = acc[i][5] + bv[5];
                o1.z = acc[i][6] + bv[6]; o1.w = acc[i][7] + bv[7];
                *(float4*)qp = o0;
                *(float4*)(qp + 4) = o1;
            }
        }
    } else if (bid < ng + nq + na) {
        // ---------------- attention: 4 waves, wave w -> step tbase+w ----------------
        int row = bid - ng - nq;              // 0..4607
        int w = tid >> 6, lane = tid & 63;
        int tc = tbase + w;
        const float* q = Q5 + ((size_t)row * 5 + (tc % 5)) * 512 + lane * 8;
        const float* ctxr = ctx + ((size_t)row * PLY) * 512 + lane * 8;
        float qv[8], vv[8];
        *(float4*)&qv[0] = *(const float4*)(q);
        *(float4*)&qv[4] = *(const float4*)(q + 4);
        *(float4*)&vv[0] = *(const float4*)(vvec + lane * 8);
        *(float4*)&vv[4] = *(const float4*)(vvec + lane * 8 + 4);

        for (int p = 0; p < PLY; ++p) {
            const float* cp = ctxr + (size_t)p * 512;
            float cv[8];
            *(float4*)&cv[0] = *(const float4*)(cp);
            *(float4*)&cv[4] = *(const float4*)(cp + 4);
            float acc = 0.0f;
            #pragma unroll
            for (int j = 0; j < 8; ++j) acc += tanhf(qv[j] + cv[j]) * vv[j];
            #pragma unroll
            for (int off = 1; off < 64; off <<= 1) acc += __shfl_xor(acc, off);
            if (lane == 0) scs[w][p] = acc;
        }
        __syncthreads();

        if (tid < 128) {
            int w2 = tid >> 5, l = tid & 31;
            float x = scs[w2][l];
            float bvv = x; int bi = l;
            #pragma unroll
            for (int off = 1; off < 32; off <<= 1) {
                float ov = __shfl_xor(bvv, off, 32);
                int oi = __shfl_xor(bi, off, 32);
                if (ov > bvv || (ov == bvv && oi < bi)) { bvv = ov; bi = oi; }
            }
            float s = expf(x - bvv);
            #pragma unroll
            for (int off = 1; off < 32; off <<= 1) s += __shfl_xor(s, off, 32);
            float lse = logf(s);
            int tt = tbase + w2;
            int tau = row / BROWS, r = row % BROWS;
            out[(size_t)tau * (BROWS * 1024) + (size_t)r * 1024 + tt * 32 + l] = x - bvv - lse;
            if (l == 0)
                out[(size_t)3 * (BROWS * 1024) + (size_t)tau * (BROWS * 32) + r * 32 + tt] = (float)bi;
        }
    } else {
        // ---------------- ctx GEMM: ctx = enc @ Wc^T ----------------
        int cp = bid - (ng + nq + na) + ctx_off;
        int pan = cp >> 2, cb = cp & 3;
        int tm = tid >> 4, tn = tid & 15;
        int lrow = tid >> 2, lc4 = tid & 3;

        int R0 = pan * 128 + lrow, R1 = R0 + 64;
        int tau = (pan * 128) / (BROWS * PLY);
        const float* enc = (tau == 0) ? home : (tau == 1) ? vis : team;
        int rr0 = R0 % (BROWS * PLY), r0 = rr0 >> 5, p0 = rr0 & 31;
        int rr1 = R1 % (BROWS * PLY), r1 = rr1 >> 5, p1 = rr1 & 31;
        const float* es0 = enc + (((size_t)((r0 % KW) * BSZn + r0 / KW)) * PLY + p0) * 512;
        const float* es1 = enc + (((size_t)((r1 % KW) * BSZn + r1 / KW)) * PLY + p1) * 512;
        const float* bp0 = Wc + (size_t)(cb * 128 + lrow) * 512;
        const float* bp1 = bp0 + (size_t)64 * 512;
        int h0 = (lrow >> 2) & 1, tn0 = lrow >> 3, w0 = lrow & 3;
        int n1 = lrow + 64;
        int h1 = (n1 >> 2) & 1,  tn1 = n1 >> 3,  w1 = n1 & 3;

        float acc[8][8];
        #pragma unroll
        for (int i = 0; i < 8; ++i)
            #pragma unroll
            for (int j = 0; j < 8; ++j) acc[i][j] = 0.0f;

        float4 ra0 = *(const float4*)(es0 + lc4 * 4);
        float4 ra1 = *(const float4*)(es1 + lc4 * 4);
        float4 rb0 = *(const float4*)(bp0 + lc4 * 4);
        float4 rb1 = *(const float4*)(bp1 + lc4 * 4);

        for (int it = 0; it < 32; ++it) {
            int buf = it & 1;
            #pragma unroll
            for (int j = 0; j < 4; ++j) {
                As[buf][lc4 * 4 + j][lrow]          = ((const float*)&ra0)[j];
                As[buf][lc4 * 4 + j][lrow + 64]     = ((const float*)&ra1)[j];
                Bs[buf][lc4 * 4 + j][h0][tn0 * 4 + w0] = ((const float*)&rb0)[j];
                Bs[buf][lc4 * 4 + j][h1][tn1 * 4 + w1] = ((const float*)&rb1)[j];
            }
            __syncthreads();
            if (it + 1 < 32) {
                int k2 = (it + 1) * 16 + lc4 * 4;
                ra0 = *(const float4*)(es0 + k2);
                ra1 = *(const float4*)(es1 + k2);
                rb0 = *(const float4*)(bp0 + k2);
                rb1 = *(const float4*)(bp1 + k2);
            }
            #pragma unroll
            for (int kk = 0; kk < 16; ++kk) {
                float af[8], bf[8];
                *(float4*)&af[0] = *(const float4*)&As[buf][kk][tm * 8];
                *(float4*)&af[4] = *(const float4*)&As[buf][kk][tm * 8 + 4];
                *(float4*)&bf[0] = *(const float4*)&Bs[buf][kk][0][tn * 4];
                *(float4*)&bf[4] = *(const float4*)&Bs[buf][kk][1][tn * 4];
                #pragma unroll
                for (int i = 0; i < 8; ++i)
                    #pragma unroll
                    for (int j = 0; j < 8; ++j)
                        acc[i][j] = fmaf(af[i], bf[j], acc[i][j]);
            }
        }
        int row0 = pan * 128 + tm * 8;
        int col0 = cb * 128 + tn * 8;
        #pragma unroll
        for (int i = 0; i < 8; ++i) {
            float* cr = ctx + (size_t)(row0 + i) * 512 + col0;
            float4 o0, o1;
            o0.x = acc[i][0]; o0.y = acc[i][1]; o0.z = acc[i][2]; o0.w = acc[i][3];
            o1.x = acc[i][4]; o1.y = acc[i][5]; o1.z = acc[i][6]; o1.w = acc[i][7];
            *(float4*)cr = o0;
            *(float4*)(cr + 4) = o1;
        }
    }
}

extern "C" void kernel_launch(void* const* d_in, const int* in_sizes, int n_in,
                              void* d_out, int out_size, void* d_ws, size_t ws_size,
                              hipStream_t stream)
{
    const float* home = (const float*)d_in[0];
    const int*   hidx = (const int*)d_in[1];
    const float* vis  = (const float*)d_in[2];
    const int*   vidx = (const int*)d_in[3];
    const float* team = (const float*)d_in[4];
    const int*   tidx = (const int*)d_in[5];
    const float* init_embed = (const float*)d_in[6];
    const float* W_ih = (const float*)d_in[7];
    const float* W_hh = (const float*)d_in[8];
    const float* b_ih = (const float*)d_in[9];
    const float* b_hh = (const float*)d_in[10];
    const float* Wq   = (const float*)d_in[11];
    const float* bq   = (const float*)d_in[12];
    const float* Wc   = (const float*)d_in[13];
    const float* vvec = (const float*)d_in[14];
    float* out = (float*)d_out;
    (void)in_sizes; (void)n_in; (void)out_size; (void)ws_size;

    float* ws = (float*)d_ws;
    float* W3    = ws; ws += (size_t)2560 * 1024;   // 10.5 MB
    float* bias3 = ws; ws += 2560;
    float* hbuf0 = ws; ws += (size_t)RTOT * 512;
    float* hbuf1 = ws; ws += (size_t)RTOT * 512;
    float* cst   = ws; ws += (size_t)RTOT * 512;
    float* Q5    = ws; ws += (size_t)RTOT * 5 * 512; // 47.2 MB
    float* ctx   = ws;                               // 302 MB f32; total ~387.9 MB

    const int NG = 576;    // 36 row-panels x 16 gate col-blocks (128 cols)
    const int NQ = 144;    // 36 x 4 q col-blocks
    const int NA = RTOT;   // attn blocks
    const int NCTX_PER = 1152;  // ctx blocks per launch, t=0..3 (total 4608)

    w3cat_kernel<<<2560, 256, 0, stream>>>(W_ih, W_hh, Wq, b_ih, b_hh, bq, W3, bias3);
    h0init_kernel<<<RTOT, 256, 0, stream>>>(home, vis, team, hbuf0, cst);

    for (int t = 0; t <= 32; ++t) {
        int ng = (t < 32) ? NG : 0;
        int nq = (t >= 1) ? NQ : 0;
        int tbase = (t >= 5 && t <= 29 && ((t - 5) & 3) == 0) ? (t - 5) : -1;
        int na = (tbase >= 0) ? NA : 0;
        int nc = (t < 4) ? NCTX_PER : 0;
        const float* hin = (t & 1) ? hbuf1 : hbuf0;
        float* hout = (t & 1) ? hbuf0 : hbuf1;
        step_k<<<ng + nq + na + nc, 256, 0, stream>>>(
            home, vis, team, hidx, vidx, tidx, init_embed,
            W3, bias3, Wc, hin, hout, cst, Q5, ctx, vvec, out,
            t, ng, nq, na, t * NCTX_PER, tbase);
    }
    // final attention batch: steps 28..31 (q31 written by the t=32 launch)
    step_k<<<NA, 256, 0, stream>>>(
        home, vis, team, hidx, vidx, tidx, init_embed,
        W3, bias3, Wc, hbuf0, hbuf1, cst, Q5, ctx, vvec, out,
        33, 0, 0, NA, 0, 28);
}

// Round 8
// 17216.861 us; speedup vs baseline: 2.8889x; 1.1438x over previous
//
#include <hip/hip_runtime.h>
#include <math.h>

#define KW 24
#define BSZn 64
#define PLY 32
#define BROWS 1536            // BSZ*KW rows per task
#define RTOT 4608             // 3*BROWS
#define G4 2048
#define BKT 32                // K per LDS tile

__device__ __forceinline__ float sigmoidf_(float x) { return 1.0f / (1.0f + expf(-x)); }

// W3[2560][1024]: n<2048 gate-interleaved (i,f,g,o per unit) [W_ih|W_hh];
// n>=2048: [0 | Wq[n-2048]]. bias3[2560] likewise. (R3-proven)
__global__ void w3cat_kernel(const float* __restrict__ W_ih, const float* __restrict__ W_hh,
                             const float* __restrict__ Wq, const float* __restrict__ b_ih,
                             const float* __restrict__ b_hh, const float* __restrict__ bq,
                             float* __restrict__ W3, float* __restrict__ bias3)
{
    int n = blockIdx.x;          // 0..2559
    int tid = threadIdx.x;
    float* w = W3 + (size_t)n * 1024;
    if (n < G4) {
        int src = (n & 3) * 512 + (n >> 2);
        for (int k = tid; k < 512; k += blockDim.x) {
            w[k]       = W_ih[(size_t)src * 512 + k];
            w[512 + k] = W_hh[(size_t)src * 512 + k];
        }
        if (tid == 0) bias3[n] = b_ih[src] + b_hh[src];
    } else {
        int j = n - G4;
        for (int k = tid; k < 512; k += blockDim.x) {
            w[k]       = 0.0f;
            w[512 + k] = Wq[(size_t)j * 512 + k];
        }
        if (tid == 0) bias3[n] = bq[j];
    }
}

// h0 = enc.sum(axis=1) -> hbuf0 and cst (R3-proven)
__global__ void h0init_kernel(const float* __restrict__ home, const float* __restrict__ vis,
                              const float* __restrict__ team,
                              float* __restrict__ hbuf0, float* __restrict__ cst)
{
    int row = blockIdx.x;                 // 0..4607
    int tid = threadIdx.x;                // 256
    int tau = row / BROWS, r = row % BROWS;
    int bb = r / KW, kw = r % KW;
    const float* enc = (tau == 0) ? home : (tau == 1) ? vis : team;
    const float* base = enc + ((size_t)(kw * BSZn + bb) * PLY) * 512;
    for (int e = tid; e < 512; e += blockDim.x) {
        float s = 0.0f;
        for (int p = 0; p < PLY; ++p) s += base[(size_t)p * 512 + e];
        hbuf0[(size_t)row * 512 + e] = s;
        cst[(size_t)row * 512 + e] = s;
    }
}

// ---- GEMM core conventions (both kernels below) ----
// 256 thr, 128x128 tile, BK=32, single LDS buffer, 2 barriers/tile, 8x8/thread.
// Loader: lrow=tid>>1 (one row/thread), lh=tid&1 (k-half), 4 float4 each for A and B.
// As[32][132]: store addr k*132+lrow -> lh pairs same-bank (16*132%32==0), lrow spans
//   32 banks once: 2-way free. Reads broadcast (4 distinct addrs/instr): free.
// Bs[32][2][73]: col n -> [h=(n>>2)&1][(n>>3)*4 + (n&3)]. Reads: Bs[kk][h][tn*4],
//   tn=0..15 stride 4 dwords over 64 -> exactly 2-way: free. Stores <=2-way.
// R6 lesson: no 2nd __launch_bounds__ arg (it caps VGPR -> spill storm).

// ---- step GEMM: gates (bid<ng) + q (bid>=ng), LSTM / Q4 epilogues fused ----
__global__ __launch_bounds__(256) void gemm_step(
    const float* __restrict__ home, const float* __restrict__ vis, const float* __restrict__ team,
    const int* __restrict__ hidx, const int* __restrict__ vidx, const int* __restrict__ tidx,
    const float* __restrict__ init_embed,
    const float* __restrict__ W3, const float* __restrict__ bias3,
    const float* __restrict__ hin, float* __restrict__ hout,
    float* __restrict__ cst, float* __restrict__ Q4, int t, int ng)
{
    __shared__ float As[BKT][132];
    __shared__ float Bs[BKT][2][73];
    int bid = blockIdx.x, tid = threadIdx.x;
    bool isg = bid < ng;
    int bm, cb, ntile, koff, nbase;
    if (isg) { bm = bid >> 4; cb = bid & 15; ntile = 32; koff = 0;   nbase = cb * 128; }
    else { int qb = bid - ng; bm = qb >> 2; cb = qb & 3; ntile = 16; koff = 512; nbase = G4 + cb * 128; }

    int lrow = tid >> 1, lh = tid & 1;
    int tm = tid >> 4, tn = tid & 15;

    int Rl = bm * 128 + lrow;
    const float* hp = hin + (size_t)Rl * 512;
    const float* xp = init_embed;
    if (isg && t > 0) {
        int tau = (bm * 128) / BROWS;
        const float* enc = (tau == 0) ? home : (tau == 1) ? vis : team;
        const int* idx = (tau == 0) ? hidx : (tau == 1) ? vidx : tidx;
        int r = Rl - tau * BROWS;
        int j = idx[r * PLY + (t - 1)];
        xp = enc + (((size_t)((r % KW) * BSZn + r / KW)) * PLY + j) * 512;
    }
    const float* brow = W3 + (size_t)(nbase + lrow) * 1024 + koff;
    int h0 = (lrow >> 2) & 1, tp0 = lrow >> 3, w0 = lrow & 3;

    float acc[8][8];
    #pragma unroll
    for (int i = 0; i < 8; ++i)
        #pragma unroll
        for (int j = 0; j < 8; ++j) acc[i][j] = 0.0f;

    for (int tile = 0; tile < ntile; ++tile) {
        const float* asrc = isg ? (tile < 16 ? xp + tile * 32 : hp + (tile - 16) * 32)
                                : (hp + tile * 32);
        float4 a0 = *(const float4*)(asrc + lh * 16);
        float4 a1 = *(const float4*)(asrc + lh * 16 + 4);
        float4 a2 = *(const float4*)(asrc + lh * 16 + 8);
        float4 a3 = *(const float4*)(asrc + lh * 16 + 12);
        const float* bsrc = brow + tile * 32 + lh * 16;
        float4 b0 = *(const float4*)(bsrc);
        float4 b1 = *(const float4*)(bsrc + 4);
        float4 b2 = *(const float4*)(bsrc + 8);
        float4 b3 = *(const float4*)(bsrc + 12);
        __syncthreads();   // prev-tile reads done before overwrite
        #pragma unroll
        for (int j = 0; j < 4; ++j) {
            As[lh * 16 + 0  + j][lrow] = ((const float*)&a0)[j];
            As[lh * 16 + 4  + j][lrow] = ((const float*)&a1)[j];
            As[lh * 16 + 8  + j][lrow] = ((const float*)&a2)[j];
            As[lh * 16 + 12 + j][lrow] = ((const float*)&a3)[j];
            Bs[lh * 16 + 0  + j][h0][tp0 * 4 + w0] = ((const float*)&b0)[j];
            Bs[lh * 16 + 4  + j][h0][tp0 * 4 + w0] = ((const float*)&b1)[j];
            Bs[lh * 16 + 8  + j][h0][tp0 * 4 + w0] = ((const float*)&b2)[j];
            Bs[lh * 16 + 12 + j][h0][tp0 * 4 + w0] = ((const float*)&b3)[j];
        }
        __syncthreads();
        #pragma unroll
        for (int kk = 0; kk < BKT; ++kk) {
            float af[8], bf[8];
            *(float4*)&af[0] = *(const float4*)&As[kk][tm * 8];
            *(float4*)&af[4] = *(const float4*)&As[kk][tm * 8 + 4];
            *(float4*)&bf[0] = *(const float4*)&Bs[kk][0][tn * 4];
            *(float4*)&bf[4] = *(const float4*)&Bs[kk][1][tn * 4];
            #pragma unroll
            for (int i = 0; i < 8; ++i)
                #pragma unroll
                for (int j = 0; j < 8; ++j)
                    acc[i][j] = fmaf(af[i], bf[j], acc[i][j]);
        }
    }

    int row0 = bm * 128 + tm * 8;
    if (isg) {
        int gcol = cb * 128 + tn * 8;
        int u0 = gcol >> 2;
        float bv[8];
        *(float4*)&bv[0] = *(const float4*)&bias3[gcol];
        *(float4*)&bv[4] = *(const float4*)&bias3[gcol + 4];
        #pragma unroll
        for (int i = 0; i < 8; ++i) {
            int row = row0 + i;
            float2 c = *(float2*)(cst + (size_t)row * 512 + u0);
            float gi = acc[i][0] + bv[0], gf = acc[i][1] + bv[1];
            float gg = acc[i][2] + bv[2], go = acc[i][3] + bv[3];
            c.x = sigmoidf_(gf) * c.x + sigmoidf_(gi) * tanhf(gg);
            float hv0 = sigmoidf_(go) * tanhf(c.x);
            gi = acc[i][4] + bv[4]; gf = acc[i][5] + bv[5];
            gg = acc[i][6] + bv[6]; go = acc[i][7] + bv[7];
            c.y = sigmoidf_(gf) * c.y + sigmoidf_(gi) * tanhf(gg);
            float hv1 = sigmoidf_(go) * tanhf(c.y);
            *(float2*)(cst + (size_t)row * 512 + u0) = c;
            float2 hh; hh.x = hv0; hh.y = hv1;
            *(float2*)(hout + (size_t)row * 512 + u0) = hh;
        }
    } else {
        int qcol = cb * 128 + tn * 8;
        int slot = (t - 1) & 3;
        float bv[8];
        *(float4*)&bv[0] = *(const float4*)&bias3[G4 + qcol];
        *(float4*)&bv[4] = *(const float4*)&bias3[G4 + qcol + 4];
        #pragma unroll
        for (int i = 0; i < 8; ++i) {
            float* qp = Q4 + ((size_t)(row0 + i) * 4 + slot) * 512 + qcol;
            float4 o0, o1;
            o0.x = acc[i][0] + bv[0]; o0.y = acc[i][1] + bv[1];
            o0.z = acc[i][2] + bv[2]; o0.w = acc[i][3] + bv[3];
            o1.x = acc[i][4] + bv[4]; o1.y = acc[i][5] + bv[5];
            o1.z = acc[i][6] + bv[6]; o1.w = acc[i][7] + bv[7];
            *(float4*)qp = o0;
            *(float4*)(qp + 4) = o1;
        }
    }
}

// ---- ctx = enc @ Wc^T (gathered A rows), same GEMM core, K=512 ----
__global__ __launch_bounds__(256) void gemm_ctx(
    const float* __restrict__ home, const float* __restrict__ vis, const float* __restrict__ team,
    const float* __restrict__ Wc, float* __restrict__ ctx)
{
    __shared__ float As[BKT][132];
    __shared__ float Bs[BKT][2][73];
    int bid = blockIdx.x, tid = threadIdx.x;   // 4608 = 1152 pans x 4 cbs
    int pan = bid >> 2, cb = bid & 3;
    int lrow = tid >> 1, lh = tid & 1;
    int tm = tid >> 4, tn = tid & 15;

    int R = pan * 128 + lrow;
    int tau = (pan * 128) / (BROWS * PLY);
    const float* enc = (tau == 0) ? home : (tau == 1) ? vis : team;
    int rr = R % (BROWS * PLY), r = rr >> 5, p = rr & 31;
    const float* ap = enc + (((size_t)((r % KW) * BSZn + r / KW)) * PLY + p) * 512;
    const float* brow = Wc + (size_t)(cb * 128 + lrow) * 512;
    int h0 = (lrow >> 2) & 1, tp0 = lrow >> 3, w0 = lrow & 3;

    float acc[8][8];
    #pragma unroll
    for (int i = 0; i < 8; ++i)
        #pragma unroll
        for (int j = 0; j < 8; ++j) acc[i][j] = 0.0f;

    for (int tile = 0; tile < 16; ++tile) {
        const float* asrc = ap + tile * 32 + lh * 16;
        float4 a0 = *(const float4*)(asrc);
        float4 a1 = *(const float4*)(asrc + 4);
        float4 a2 = *(const float4*)(asrc + 8);
        float4 a3 = *(const float4*)(asrc + 12);
        const float* bsrc = brow + tile * 32 + lh * 16;
        float4 b0 = *(const float4*)(bsrc);
        float4 b1 = *(const float4*)(bsrc + 4);
        float4 b2 = *(const float4*)(bsrc + 8);
        float4 b3 = *(const float4*)(bsrc + 12);
        __syncthreads();
        #pragma unroll
        for (int j = 0; j < 4; ++j) {
            As[lh * 16 + 0  + j][lrow] = ((const float*)&a0)[j];
            As[lh * 16 + 4  + j][lrow] = ((const float*)&a1)[j];
            As[lh * 16 + 8  + j][lrow] = ((const float*)&a2)[j];
            As[lh * 16 + 12 + j][lrow] = ((const float*)&a3)[j];
            Bs[lh * 16 + 0  + j][h0][tp0 * 4 + w0] = ((const float*)&b0)[j];
            Bs[lh * 16 + 4  + j][h0][tp0 * 4 + w0] = ((const float*)&b1)[j];
            Bs[lh * 16 + 8  + j][h0][tp0 * 4 + w0] = ((const float*)&b2)[j];
            Bs[lh * 16 + 12 + j][h0][tp0 * 4 + w0] = ((const float*)&b3)[j];
        }
        __syncthreads();
        #pragma unroll
        for (int kk = 0; kk < BKT; ++kk) {
            float af[8], bf[8];
            *(float4*)&af[0] = *(const float4*)&As[kk][tm * 8];
            *(float4*)&af[4] = *(const float4*)&As[kk][tm * 8 + 4];
            *(float4*)&bf[0] = *(const float4*)&Bs[kk][0][tn * 4];
            *(float4*)&bf[4] = *(const float4*)&Bs[kk][1][tn * 4];
            #pragma unroll
            for (int i = 0; i < 8; ++i)
                #pragma unroll
                for (int j = 0; j < 8; ++j)
                    acc[i][j] = fmaf(af[i], bf[j], acc[i][j]);
        }
    }
    int row0 = pan * 128 + tm * 8;
    int col0 = cb * 128 + tn * 8;
    #pragma unroll
    for (int i = 0; i < 8; ++i) {
        float* cr = ctx + (size_t)(row0 + i) * 512 + col0;
        float4 o0, o1;
        o0.x = acc[i][0]; o0.y = acc[i][1]; o0.z = acc[i][2]; o0.w = acc[i][3];
        o1.x = acc[i][4]; o1.y = acc[i][5]; o1.z = acc[i][6]; o1.w = acc[i][7];
        *(float4*)cr = o0;
        *(float4*)(cr + 4) = o1;
    }
}

// ---- batched attention for 4 steps (R3-proven, separate launch) ----
__global__ __launch_bounds__(256) void attn4_kernel(
    const float* __restrict__ Q4, const float* __restrict__ ctx,
    const float* __restrict__ vvec, float* __restrict__ out, int tbase)
{
    int row = blockIdx.x;                 // 0..4607
    int tid = threadIdx.x;
    int w = tid >> 6, lane = tid & 63;    // wave w -> step tbase+w (slot == w, tbase%4==0)
    __shared__ float sc_s[4][PLY];

    const float* q = Q4 + (size_t)row * 2048 + (size_t)w * 512 + lane * 8;
    const float* ctxr = ctx + (size_t)row * PLY * 512 + lane * 8;
    float qv[8], vv[8];
    *(float4*)&qv[0] = *(const float4*)(q);
    *(float4*)&qv[4] = *(const float4*)(q + 4);
    *(float4*)&vv[0] = *(const float4*)(vvec + lane * 8);
    *(float4*)&vv[4] = *(const float4*)(vvec + lane * 8 + 4);

    for (int p = 0; p < PLY; ++p) {
        const float* cp = ctxr + (size_t)p * 512;
        float cv[8];
        *(float4*)&cv[0] = *(const float4*)(cp);
        *(float4*)&cv[4] = *(const float4*)(cp + 4);
        float acc = 0.0f;
        #pragma unroll
        for (int j = 0; j < 8; ++j) acc += tanhf(qv[j] + cv[j]) * vv[j];
        #pragma unroll
        for (int off = 1; off < 64; off <<= 1) acc += __shfl_xor(acc, off);
        if (lane == 0) sc_s[w][p] = acc;
    }
    __syncthreads();

    if (tid < 128) {
        int w2 = tid >> 5, l = tid & 31;
        float x = sc_s[w2][l];
        float bvv = x; int bi = l;
        #pragma unroll
        for (int off = 1; off < 32; off <<= 1) {
            float ov = __shfl_xor(bvv, off, 32);
            int oi = __shfl_xor(bi, off, 32);
            if (ov > bvv || (ov == bvv && oi < bi)) { bvv = ov; bi = oi; }
        }
        float s = expf(x - bvv);
        #pragma unroll
        for (int off = 1; off < 32; off <<= 1) s += __shfl_xor(s, off, 32);
        float lse = logf(s);
        int t = tbase + w2;
        int tau = row / BROWS, r = row % BROWS;
        out[(size_t)tau * (BROWS * 1024) + (size_t)r * 1024 + t * 32 + l] = x - bvv - lse;
        if (l == 0)
            out[(size_t)3 * (BROWS * 1024) + (size_t)tau * (BROWS * 32) + r * 32 + t] = (float)bi;
    }
}

extern "C" void kernel_launch(void* const* d_in, const int* in_sizes, int n_in,
                              void* d_out, int out_size, void* d_ws, size_t ws_size,
                              hipStream_t stream)
{
    const float* home = (const float*)d_in[0];
    const int*   hidx = (const int*)d_in[1];
    const float* vis  = (const float*)d_in[2];
    const int*   vidx = (const int*)d_in[3];
    const float* team = (const float*)d_in[4];
    const int*   tidx = (const int*)d_in[5];
    const float* init_embed = (const float*)d_in[6];
    const float* W_ih = (const float*)d_in[7];
    const float* W_hh = (const float*)d_in[8];
    const float* b_ih = (const float*)d_in[9];
    const float* b_hh = (const float*)d_in[10];
    const float* Wq   = (const float*)d_in[11];
    const float* bq   = (const float*)d_in[12];
    const float* Wc   = (const float*)d_in[13];
    const float* vvec = (const float*)d_in[14];
    float* out = (float*)d_out;
    (void)in_sizes; (void)n_in; (void)out_size; (void)ws_size;

    float* ws = (float*)d_ws;
    float* W3    = ws; ws += (size_t)2560 * 1024;    // 10.5 MB
    float* bias3 = ws; ws += 2560;
    float* hbuf0 = ws; ws += (size_t)RTOT * 512;
    float* hbuf1 = ws; ws += (size_t)RTOT * 512;
    float* cst   = ws; ws += (size_t)RTOT * 512;
    float* Q4    = ws; ws += (size_t)RTOT * 4 * 512; // 37.7 MB
    float* ctx   = ws;                               // 302 MB f32; total ~378 MB

    const int NG = 576;    // 36 row-panels x 16 gate col-blocks
    const int NQ = 144;    // 36 x 4 q col-blocks

    w3cat_kernel<<<2560, 256, 0, stream>>>(W_ih, W_hh, Wq, b_ih, b_hh, bq, W3, bias3);
    h0init_kernel<<<RTOT, 256, 0, stream>>>(home, vis, team, hbuf0, cst);
    gemm_ctx<<<(RTOT * PLY / 128) * 4, 256, 0, stream>>>(home, vis, team, Wc, ctx); // 4608

    for (int t = 0; t < 32; ++t) {
        const float* hin = (t & 1) ? hbuf1 : hbuf0;
        float* hout = (t & 1) ? hbuf0 : hbuf1;
        int nq = (t >= 1) ? NQ : 0;
        gemm_step<<<NG + nq, 256, 0, stream>>>(
            home, vis, team, hidx, vidx, tidx, init_embed,
            W3, bias3, hin, hout, cst, Q4, t, NG);
        if (t >= 4 && (t & 3) == 0)
            attn4_kernel<<<RTOT, 256, 0, stream>>>(Q4, ctx, vvec, out, t - 4);
    }
    // q31 from h31 (in hbuf0: t=31 odd wrote hout=hbuf0); q blocks only
    gemm_step<<<NQ, 256, 0, stream>>>(
        home, vis, team, hidx, vidx, tidx, init_embed,
        W3, bias3, hbuf0, hbuf1, cst, Q4, 32, 0);
    attn4_kernel<<<RTOT, 256, 0, stream>>>(Q4, ctx, vvec, out, 28);
}

// Round 9
// 11715.118 us; speedup vs baseline: 4.2456x; 1.4696x over previous
//
#include <hip/hip_runtime.h>
#include <hip/hip_bf16.h>
#include <math.h>

#define KW 24
#define BSZn 64
#define PLY 32
#define BROWS 1536            // BSZ*KW rows per task
#define RTOT 4608             // 3*BROWS

typedef __attribute__((ext_vector_type(8))) short short8v;  // 8 bf16 (4 VGPRs)
typedef __attribute__((ext_vector_type(4))) float f32x4;

__device__ __forceinline__ float sigmoidf_(float x) { return 1.0f / (1.0f + expf(-x)); }

// exact 3-way bf16 split: v = s0 + s1 + s2 + O(2^-26 v)
__device__ __forceinline__ void split3(float v, ushort* a, ushort* b, ushort* c)
{
    __hip_bfloat16 h1 = __float2bfloat16(v);  float f1 = __bfloat162float(h1);
    float r1 = v - f1;
    __hip_bfloat16 h2 = __float2bfloat16(r1); float f2 = __bfloat162float(h2);
    float r2 = r1 - f2;
    __hip_bfloat16 h3 = __float2bfloat16(r2);
    *a = *(ushort*)&h1; *b = *(ushort*)&h2; *c = *(ushort*)&h3;
}

// ---- weights prep ----
// Gate cols layout: n = ublk*64 + gate*16 + ui  (ublk=unit>>4, ui=unit&15)
// so a 64-col wave strip = one ublk, frag fn = gate. Source row = gate*512 + unit.
// biasG kept in original [gate*512 + unit] layout.
__global__ void prep_split(const float* __restrict__ W_ih, const float* __restrict__ W_hh,
                           const float* __restrict__ Wq,
                           const float* __restrict__ b_ih, const float* __restrict__ b_hh,
                           ushort* __restrict__ Wg0, ushort* __restrict__ Wg1, ushort* __restrict__ Wg2,
                           ushort* __restrict__ Wq0, ushort* __restrict__ Wq1, ushort* __restrict__ Wq2,
                           float* __restrict__ biasG)
{
    int n = blockIdx.x, tid = threadIdx.x;     // 0..2559
    if (n < 2048) {
        int ublk = n >> 6, gate = (n >> 4) & 3, ui = n & 15;
        int src = gate * 512 + ublk * 16 + ui;
        for (int k = tid; k < 1024; k += 256) {
            float v = (k < 512) ? W_ih[(size_t)src * 512 + k]
                                : W_hh[(size_t)src * 512 + (k - 512)];
            ushort s0, s1, s2; split3(v, &s0, &s1, &s2);
            Wg0[(size_t)n * 1024 + k] = s0;
            Wg1[(size_t)n * 1024 + k] = s1;
            Wg2[(size_t)n * 1024 + k] = s2;
        }
        if (tid == 0) biasG[src] = b_ih[src] + b_hh[src];
    } else {
        int n2 = n - 2048;
        for (int k = tid; k < 512; k += 256) {
            ushort s0, s1, s2; split3(Wq[(size_t)n2 * 512 + k], &s0, &s1, &s2);
            Wq0[(size_t)n2 * 512 + k] = s0;
            Wq1[(size_t)n2 * 512 + k] = s1;
            Wq2[(size_t)n2 * 512 + k] = s2;
        }
    }
}

// ---- init: cst = h0 = enc.sum(axis=1); hsplit[1] = split(h0); xsplit = split(init_embed) ----
__global__ void initsplit(const float* __restrict__ home, const float* __restrict__ vis,
                          const float* __restrict__ team, const float* __restrict__ init_embed,
                          float* __restrict__ cst,
                          ushort* __restrict__ h0_, ushort* __restrict__ h1_, ushort* __restrict__ h2_,
                          ushort* __restrict__ x0_, ushort* __restrict__ x1_, ushort* __restrict__ x2_)
{
    int row = blockIdx.x, tid = threadIdx.x;
    int tau = row / BROWS, r = row % BROWS;
    const float* enc = (tau == 0) ? home : (tau == 1) ? vis : team;
    const float* base = enc + ((size_t)((r % KW) * BSZn + r / KW) * PLY) * 512;
    for (int e = tid; e < 512; e += 256) {
        float s = 0.0f;
        for (int p = 0; p < PLY; ++p) s += base[(size_t)p * 512 + e];
        size_t o = (size_t)row * 512 + e;
        cst[o] = s;
        ushort a, b, c;
        split3(s, &a, &b, &c);
        h0_[o] = a; h1_[o] = b; h2_[o] = c;
        split3(init_embed[e], &a, &b, &c);
        x0_[o] = a; x1_[o] = b; x2_[o] = c;
    }
}

// ---- gather x_{t+1} and split (idx[.][t]) ----
__global__ void xprep(const float* __restrict__ home, const float* __restrict__ vis,
                      const float* __restrict__ team,
                      const int* __restrict__ hidx, const int* __restrict__ vidx,
                      const int* __restrict__ tidx,
                      ushort* __restrict__ x0_, ushort* __restrict__ x1_, ushort* __restrict__ x2_,
                      int t)
{
    int row = blockIdx.x, tid = threadIdx.x;
    int tau = row / BROWS, r = row % BROWS;
    const float* enc = (tau == 0) ? home : (tau == 1) ? vis : team;
    const int* idx = (tau == 0) ? hidx : (tau == 1) ? vidx : tidx;
    int j = idx[r * PLY + t];
    const float* src = enc + ((size_t)((r % KW) * BSZn + r / KW) * PLY + j) * 512;
    for (int e = tid; e < 512; e += 256) {
        size_t o = (size_t)row * 512 + e;
        ushort a, b, c; split3(src[e], &a, &b, &c);
        x0_[o] = a; x1_[o] = b; x2_[o] = c;
    }
}

// ---- gates MFMA: C = [x|h] @ W3g^T (6 split passes), LSTM fused in epilogue ----
// 128x128 block, 4 waves (2x2 quadrants of 64x64), 16x16x32 bf16 MFMA, BK=32.
__global__ __launch_bounds__(256) void gates_mfma(
    const ushort* __restrict__ x0_, const ushort* __restrict__ x1_, const ushort* __restrict__ x2_,
    const ushort* __restrict__ hi0, const ushort* __restrict__ hi1, const ushort* __restrict__ hi2,
    const ushort* __restrict__ Wg0, const ushort* __restrict__ Wg1, const ushort* __restrict__ Wg2,
    const float* __restrict__ biasG, float* __restrict__ cst,
    ushort* __restrict__ ho0, ushort* __restrict__ ho1, ushort* __restrict__ ho2)
{
    __shared__ float4 LdsBuf[1024];           // 16 KB: A tile [0,8K), B tile [8K,16K)
    char* LdsA = (char*)LdsBuf;
    char* LdsB = LdsA + 8192;
    int tid = threadIdx.x;
    int bm = blockIdx.x, bn = blockIdx.y;
    int w = tid >> 6, lane = tid & 63;
    int wr = w >> 1, wc = w & 1;
    int r0 = bm * 128;
    int nbase = bn * 128;
    int srow = tid >> 1, sh = tid & 1;        // stager: row 0..127, 32B half

    const ushort* Ax[3] = {x0_, x1_, x2_};
    const ushort* Ah[3] = {hi0, hi1, hi2};
    const ushort* Bg[3] = {Wg0, Wg1, Wg2};
    const int pa[6] = {0, 2, 1, 0, 1, 0};     // smallest products first
    const int pb[6] = {2, 0, 1, 1, 0, 0};

    f32x4 acc[4][4];
    #pragma unroll
    for (int i = 0; i < 4; ++i)
        #pragma unroll
        for (int j = 0; j < 4; ++j) acc[i][j] = (f32x4){0.f, 0.f, 0.f, 0.f};

    for (int p = 0; p < 6; ++p) {
        const ushort* Axp = Ax[pa[p]];
        const ushort* Ahp = Ah[pa[p]];
        const ushort* Bb  = Bg[pb[p]] + (size_t)nbase * 1024;
        for (int kb = 0; kb < 32; ++kb) {
            const ushort* Abase = (kb < 16) ? Axp : Ahp;
            int kloc = (kb & 15) * 32;
            const ushort* as = Abase + (size_t)(r0 + srow) * 512 + kloc + sh * 16;
            uint4 a0 = *(const uint4*)as;
            uint4 a1 = *(const uint4*)(as + 8);
            const ushort* bs = Bb + (size_t)srow * 1024 + kb * 32 + sh * 16;
            uint4 b0 = *(const uint4*)bs;
            uint4 b1 = *(const uint4*)(bs + 8);
            __syncthreads();                  // prev iteration's frag reads done
            *(uint4*)(LdsA + srow * 64 + sh * 32)      = a0;
            *(uint4*)(LdsA + srow * 64 + sh * 32 + 16) = a1;
            *(uint4*)(LdsB + srow * 64 + sh * 32)      = b0;
            *(uint4*)(LdsB + srow * 64 + sh * 32 + 16) = b1;
            __syncthreads();
            short8v af[4], bf[4];
            #pragma unroll
            for (int fm = 0; fm < 4; ++fm)
                af[fm] = *(const short8v*)(LdsA + (wr * 64 + fm * 16 + (lane & 15)) * 64 + (lane >> 4) * 16);
            #pragma unroll
            for (int fn = 0; fn < 4; ++fn)
                bf[fn] = *(const short8v*)(LdsB + (wc * 64 + fn * 16 + (lane & 15)) * 64 + (lane >> 4) * 16);
            #pragma unroll
            for (int fm = 0; fm < 4; ++fm)
                #pragma unroll
                for (int fn = 0; fn < 4; ++fn)
                    acc[fm][fn] = __builtin_amdgcn_mfma_f32_16x16x32_bf16(
                        af[fm], bf[fn], acc[fm][fn], 0, 0, 0);
        }
    }

    // epilogue: frag fn == gate; unit u fixed per lane; C/D: col=lane&15, row=(lane>>4)*4+reg
    int u = (bn * 2 + wc) * 16 + (lane & 15);
    float bI = biasG[u], bF = biasG[512 + u], bG = biasG[1024 + u], bO = biasG[1536 + u];
    #pragma unroll
    for (int fm = 0; fm < 4; ++fm) {
        #pragma unroll
        for (int reg = 0; reg < 4; ++reg) {
            int row = r0 + wr * 64 + fm * 16 + (lane >> 4) * 4 + reg;
            float gi = acc[fm][0][reg] + bI;
            float gf = acc[fm][1][reg] + bF;
            float gg = acc[fm][2][reg] + bG;
            float go = acc[fm][3][reg] + bO;
            size_t ci = (size_t)row * 512 + u;
            float c = cst[ci];
            c = sigmoidf_(gf) * c + sigmoidf_(gi) * tanhf(gg);
            float h = sigmoidf_(go) * tanhf(c);
            cst[ci] = c;
            ushort s0, s1, s2; split3(h, &s0, &s1, &s2);
            ho0[ci] = s0; ho1[ci] = s1; ho2[ci] = s2;
        }
    }
}

// ---- q MFMA: q = h @ Wq^T + bq (6 passes, K=512) -> Q2 slot ----
__global__ __launch_bounds__(256) void q_mfma(
    const ushort* __restrict__ hi0, const ushort* __restrict__ hi1, const ushort* __restrict__ hi2,
    const ushort* __restrict__ Wq0, const ushort* __restrict__ Wq1, const ushort* __restrict__ Wq2,
    const float* __restrict__ bq, float* __restrict__ Qout)
{
    __shared__ float4 LdsBuf[1024];
    char* LdsA = (char*)LdsBuf;
    char* LdsB = LdsA + 8192;
    int tid = threadIdx.x;
    int bm = blockIdx.x, bn = blockIdx.y;
    int w = tid >> 6, lane = tid & 63;
    int wr = w >> 1, wc = w & 1;
    int r0 = bm * 128;
    int nbase = bn * 128;
    int srow = tid >> 1, sh = tid & 1;

    const ushort* Ah[3] = {hi0, hi1, hi2};
    const ushort* Bg[3] = {Wq0, Wq1, Wq2};
    const int pa[6] = {0, 2, 1, 0, 1, 0};
    const int pb[6] = {2, 0, 1, 1, 0, 0};

    f32x4 acc[4][4];
    #pragma unroll
    for (int i = 0; i < 4; ++i)
        #pragma unroll
        for (int j = 0; j < 4; ++j) acc[i][j] = (f32x4){0.f, 0.f, 0.f, 0.f};

    for (int p = 0; p < 6; ++p) {
        const ushort* Ap = Ah[pa[p]];
        const ushort* Bb = Bg[pb[p]] + (size_t)nbase * 512;
        for (int kb = 0; kb < 16; ++kb) {
            const ushort* as = Ap + (size_t)(r0 + srow) * 512 + kb * 32 + sh * 16;
            uint4 a0 = *(const uint4*)as;
            uint4 a1 = *(const uint4*)(as + 8);
            const ushort* bs = Bb + (size_t)srow * 512 + kb * 32 + sh * 16;
            uint4 b0 = *(const uint4*)bs;
            uint4 b1 = *(const uint4*)(bs + 8);
            __syncthreads();
            *(uint4*)(LdsA + srow * 64 + sh * 32)      = a0;
            *(uint4*)(LdsA + srow * 64 + sh * 32 + 16) = a1;
            *(uint4*)(LdsB + srow * 64 + sh * 32)      = b0;
            *(uint4*)(LdsB + srow * 64 + sh * 32 + 16) = b1;
            __syncthreads();
            short8v af[4], bf[4];
            #pragma unroll
            for (int fm = 0; fm < 4; ++fm)
                af[fm] = *(const short8v*)(LdsA + (wr * 64 + fm * 16 + (lane & 15)) * 64 + (lane >> 4) * 16);
            #pragma unroll
            for (int fn = 0; fn < 4; ++fn)
                bf[fn] = *(const short8v*)(LdsB + (wc * 64 + fn * 16 + (lane & 15)) * 64 + (lane >> 4) * 16);
            #pragma unroll
            for (int fm = 0; fm < 4; ++fm)
                #pragma unroll
                for (int fn = 0; fn < 4; ++fn)
                    acc[fm][fn] = __builtin_amdgcn_mfma_f32_16x16x32_bf16(
                        af[fm], bf[fn], acc[fm][fn], 0, 0, 0);
        }
    }

    #pragma unroll
    for (int fn = 0; fn < 4; ++fn) {
        int col = nbase + wc * 64 + fn * 16 + (lane & 15);
        float bqv = bq[col];
        #pragma unroll
        for (int fm = 0; fm < 4; ++fm)
            #pragma unroll
            for (int reg = 0; reg < 4; ++reg) {
                int row = r0 + wr * 64 + fm * 16 + (lane >> 4) * 4 + reg;
                Qout[(size_t)row * 512 + col] = acc[fm][fn][reg] + bqv;
            }
    }
}

// ---- ctx = enc @ Wc^T, f32 (R1-proven kernel, verbatim structure) ----
#define BM 128
#define BN 128
#define BKK 16
__global__ __launch_bounds__(256) void gemm_ctx(
    const float* __restrict__ A0, const float* __restrict__ A1, const float* __restrict__ A2,
    const float* __restrict__ B, float* __restrict__ C)
{
    __shared__ float As[BKK][BM + 4];
    __shared__ float Bs[BKK][BN + 4];
    int bm = blockIdx.x, bn = blockIdx.y;
    int tid = threadIdx.x;
    int tm = tid >> 4, tn = tid & 15;
    int lrow = tid >> 2, lc4 = tid & 3;

    int R0 = bm * BM;
    int tau = R0 / (BROWS * PLY);
    const float* enc = (tau == 0) ? A0 : (tau == 1) ? A1 : A2;
    int R = R0 + lrow;
    int rr = R % (BROWS * PLY); int r = rr >> 5; int p = rr & 31;
    const float* a_src0 = enc + (((size_t)((r % KW) * BSZn + r / KW)) * PLY + p) * 512;
    R = R0 + lrow + 64;
    rr = R % (BROWS * PLY); r = rr >> 5; p = rr & 31;
    const float* a_src1 = enc + (((size_t)((r % KW) * BSZn + r / KW)) * PLY + p) * 512;
    const float* b_src0 = B + (size_t)(bn * BN + lrow) * 512;
    const float* b_src1 = b_src0 + (size_t)64 * 512;

    float acc[8][8];
    #pragma unroll
    for (int i = 0; i < 8; ++i)
        #pragma unroll
        for (int j = 0; j < 8; ++j) acc[i][j] = 0.0f;

    float4 a0 = *(const float4*)(a_src0 + lc4 * 4);
    float4 a1 = *(const float4*)(a_src1 + lc4 * 4);
    float4 b0 = *(const float4*)(b_src0 + lc4 * 4);
    float4 b1 = *(const float4*)(b_src1 + lc4 * 4);

    for (int t = 0; t < 512 / BKK; ++t) {
        __syncthreads();
        As[lc4 * 4 + 0][lrow] = a0.x; As[lc4 * 4 + 1][lrow] = a0.y;
        As[lc4 * 4 + 2][lrow] = a0.z; As[lc4 * 4 + 3][lrow] = a0.w;
        As[lc4 * 4 + 0][lrow + 64] = a1.x; As[lc4 * 4 + 1][lrow + 64] = a1.y;
        As[lc4 * 4 + 2][lrow + 64] = a1.z; As[lc4 * 4 + 3][lrow + 64] = a1.w;
        Bs[lc4 * 4 + 0][lrow] = b0.x; Bs[lc4 * 4 + 1][lrow] = b0.y;
        Bs[lc4 * 4 + 2][lrow] = b0.z; Bs[lc4 * 4 + 3][lrow] = b0.w;
        Bs[lc4 * 4 + 0][lrow + 64] = b1.x; Bs[lc4 * 4 + 1][lrow + 64] = b1.y;
        Bs[lc4 * 4 + 2][lrow + 64] = b1.z; Bs[lc4 * 4 + 3][lrow + 64] = b1.w;
        __syncthreads();
        if (t + 1 < 512 / BKK) {
            int k0 = (t + 1) * BKK + lc4 * 4;
            a0 = *(const float4*)(a_src0 + k0);
            a1 = *(const float4*)(a_src1 + k0);
            b0 = *(const float4*)(b_src0 + k0);
            b1 = *(const float4*)(b_src1 + k0);
        }
        #pragma unroll
        for (int k = 0; k < BKK; ++k) {
            float af[8], bf[8];
            *(float4*)&af[0] = *(const float4*)&As[k][tm * 8];
            *(float4*)&af[4] = *(const float4*)&As[k][tm * 8 + 4];
            *(float4*)&bf[0] = *(const float4*)&Bs[k][tn * 8];
            *(float4*)&bf[4] = *(const float4*)&Bs[k][tn * 8 + 4];
            #pragma unroll
            for (int i = 0; i < 8; ++i)
                #pragma unroll
                for (int j = 0; j < 8; ++j)
                    acc[i][j] = fmaf(af[i], bf[j], acc[i][j]);
        }
    }
    int row0 = bm * BM + tm * 8;
    int col0 = bn * BN + tn * 8;
    #pragma unroll
    for (int i = 0; i < 8; ++i) {
        float* cr = C + (size_t)(row0 + i) * 512 + col0;
        float4 o0, o1;
        o0.x = acc[i][0]; o0.y = acc[i][1]; o0.z = acc[i][2]; o0.w = acc[i][3];
        o1.x = acc[i][4]; o1.y = acc[i][5]; o1.z = acc[i][6]; o1.w = acc[i][7];
        *(float4*)cr = o0;
        *(float4*)(cr + 4) = o1;
    }
}

// ---- attention for 2 steps (tbase, tbase+1), f32, log_softmax + argmax ----
__global__ __launch_bounds__(256) void attn2(
    const float* __restrict__ Q2, const float* __restrict__ ctx,
    const float* __restrict__ vvec, float* __restrict__ out, int tbase)
{
    int row = blockIdx.x, tid = threadIdx.x;
    int w = tid >> 6, lane = tid & 63;
    int step = w >> 1;                         // waves 0,1 -> step 0; 2,3 -> step 1
    int tt = tbase + step;
    __shared__ float scs[2][PLY];

    const float* q = Q2 + (size_t)(tt & 1) * RTOT * 512 + (size_t)row * 512 + lane * 8;
    const float* ctxr = ctx + (size_t)row * PLY * 512 + lane * 8;
    float qv[8], vv[8];
    *(float4*)&qv[0] = *(const float4*)(q);
    *(float4*)&qv[4] = *(const float4*)(q + 4);
    *(float4*)&vv[0] = *(const float4*)(vvec + lane * 8);
    *(float4*)&vv[4] = *(const float4*)(vvec + lane * 8 + 4);

    for (int pp = 0; pp < 16; ++pp) {
        int p = (w & 1) * 16 + pp;
        const float* cp = ctxr + (size_t)p * 512;
        float cv[8];
        *(float4*)&cv[0] = *(const float4*)(cp);
        *(float4*)&cv[4] = *(const float4*)(cp + 4);
        float acc = 0.0f;
        #pragma unroll
        for (int j = 0; j < 8; ++j) acc += tanhf(qv[j] + cv[j]) * vv[j];
        #pragma unroll
        for (int off = 1; off < 64; off <<= 1) acc += __shfl_xor(acc, off);
        if (lane == 0) scs[step][p] = acc;
    }
    __syncthreads();

    if (tid < 64) {
        int w2 = tid >> 5, l = tid & 31;
        float x = scs[w2][l];
        float bvv = x; int bi = l;
        #pragma unroll
        for (int off = 1; off < 32; off <<= 1) {
            float ov = __shfl_xor(bvv, off, 32);
            int oi = __shfl_xor(bi, off, 32);
            if (ov > bvv || (ov == bvv && oi < bi)) { bvv = ov; bi = oi; }
        }
        float s = expf(x - bvv);
        #pragma unroll
        for (int off = 1; off < 32; off <<= 1) s += __shfl_xor(s, off, 32);
        float lse = logf(s);
        int t = tbase + w2;
        int tau = row / BROWS, r = row % BROWS;
        out[(size_t)tau * (BROWS * 1024) + (size_t)r * 1024 + t * 32 + l] = x - bvv - lse;
        if (l == 0)
            out[(size_t)3 * (BROWS * 1024) + (size_t)tau * (BROWS * 32) + r * 32 + t] = (float)bi;
    }
}

extern "C" void kernel_launch(void* const* d_in, const int* in_sizes, int n_in,
                              void* d_out, int out_size, void* d_ws, size_t ws_size,
                              hipStream_t stream)
{
    const float* home = (const float*)d_in[0];
    const int*   hidx = (const int*)d_in[1];
    const float* vis  = (const float*)d_in[2];
    const int*   vidx = (const int*)d_in[3];
    const float* team = (const float*)d_in[4];
    const int*   tidx = (const int*)d_in[5];
    const float* init_embed = (const float*)d_in[6];
    const float* W_ih = (const float*)d_in[7];
    const float* W_hh = (const float*)d_in[8];
    const float* b_ih = (const float*)d_in[9];
    const float* b_hh = (const float*)d_in[10];
    const float* Wq   = (const float*)d_in[11];
    const float* bq   = (const float*)d_in[12];
    const float* Wc   = (const float*)d_in[13];
    const float* vvec = (const float*)d_in[14];
    float* out = (float*)d_out;
    (void)in_sizes; (void)n_in; (void)out_size; (void)ws_size;

    char* wsb = (char*)d_ws;
    float* ctx   = (float*)wsb; wsb += (size_t)RTOT * PLY * 512 * 4;   // 302.0 MB
    float* cst   = (float*)wsb; wsb += (size_t)RTOT * 512 * 4;         // 9.4 MB
    float* Q2    = (float*)wsb; wsb += (size_t)2 * RTOT * 512 * 4;     // 18.9 MB
    float* biasG = (float*)wsb; wsb += 2048 * 4;
    ushort* Wg[3], *Wq3[3], *xs[3], *hs[2][3];
    for (int i = 0; i < 3; ++i) { Wg[i]  = (ushort*)wsb; wsb += (size_t)2048 * 1024 * 2; }
    for (int i = 0; i < 3; ++i) { Wq3[i] = (ushort*)wsb; wsb += (size_t)512 * 512 * 2; }
    for (int i = 0; i < 3; ++i) { xs[i]  = (ushort*)wsb; wsb += (size_t)RTOT * 512 * 2; }
    for (int b = 0; b < 2; ++b)
        for (int i = 0; i < 3; ++i) { hs[b][i] = (ushort*)wsb; wsb += (size_t)RTOT * 512 * 2; }
    // total ~386.9 MB (< 387.97 MB proven in R1)

    prep_split<<<2560, 256, 0, stream>>>(W_ih, W_hh, Wq, b_ih, b_hh,
                                         Wg[0], Wg[1], Wg[2], Wq3[0], Wq3[1], Wq3[2], biasG);
    initsplit<<<RTOT, 256, 0, stream>>>(home, vis, team, init_embed, cst,
                                        hs[1][0], hs[1][1], hs[1][2],
                                        xs[0], xs[1], xs[2]);
    gemm_ctx<<<dim3(RTOT * PLY / BM, 512 / BN), 256, 0, stream>>>(home, vis, team, Wc, ctx);

    for (int t = 0; t < 32; ++t) {
        int hin = (t + 1) & 1, hout = t & 1;
        gates_mfma<<<dim3(36, 16), 256, 0, stream>>>(
            xs[0], xs[1], xs[2],
            hs[hin][0], hs[hin][1], hs[hin][2],
            Wg[0], Wg[1], Wg[2], biasG, cst,
            hs[hout][0], hs[hout][1], hs[hout][2]);
        if (t < 31)
            xprep<<<RTOT, 256, 0, stream>>>(home, vis, team, hidx, vidx, tidx,
                                            xs[0], xs[1], xs[2], t);
        q_mfma<<<dim3(36, 4), 256, 0, stream>>>(
            hs[hout][0], hs[hout][1], hs[hout][2],
            Wq3[0], Wq3[1], Wq3[2], bq,
            Q2 + (size_t)(t & 1) * RTOT * 512);
        if (t & 1)
            attn2<<<RTOT, 256, 0, stream>>>(Q2, ctx, vvec, out, t - 1);
    }
}